// Round 4
// baseline (304.807 us; speedup 1.0000x reference)
//
#include <hip/hip_runtime.h>

#define NBOX   32
#define NCH    32
#define IMG    256
#define CROPH  28
#define OUTHW  224
#define MAXCAP 256   // widths are clipped to W=256

// ===========================================================================
// Lane-exact scalar emulation of x86-simd-sort (numpy >=2.x vendored version,
// xss_network_keyvaluesort.hpp) avx512 argsort for N=32 int64 keys.
// Tie rules: cmp_merge keeps each lane's own index when tmp==in1;
// COEX: min side <- FIRST operand's index, max side <- SECOND's, on ties.
// ===========================================================================
__device__ __forceinline__ void xss_stage(long long* k, int* a,
                                          const int* p, int mask) {
  long long nk[8]; int na[8];
  for (int j = 0; j < 8; ++j) {
    long long kb = k[p[j]]; int ab = a[p[j]];
    long long mn = (kb < k[j]) ? kb : k[j];
    long long mx = (kb < k[j]) ? k[j] : kb;
    long long sel = ((mask >> j) & 1) ? mx : mn;
    na[j] = (sel == k[j]) ? a[j] : ab;   // eq(tmp,in1) -> keep own index
    nk[j] = sel;
  }
  for (int j = 0; j < 8; ++j) { k[j] = nk[j]; a[j] = na[j]; }
}

__device__ __forceinline__ void xss_rev(long long* k, int* a) {
  for (int j = 0; j < 4; ++j) {
    long long tk = k[j]; k[j] = k[7-j]; k[7-j] = tk;
    int ta = a[j]; a[j] = a[7-j]; a[7-j] = ta;
  }
}

// COEX: v1 <- min (tie keeps v1's index), v2 <- max (tie keeps v2's index)
__device__ __forceinline__ void xss_coex(long long* k1, int* a1,
                                         long long* k2, int* a2) {
  for (int j = 0; j < 8; ++j) {
    long long ka = k1[j], kb = k2[j];
    int aa = a1[j], ab = a2[j];
    bool alem = (ka <= kb);
    k1[j] = alem ? ka : kb;  a1[j] = alem ? aa : ab;
    k2[j] = alem ? kb : ka;  a2[j] = alem ? ab : aa;
  }
}

__device__ __forceinline__ void xss_sort8(long long* k, int* a) {
  const int P1[8] = {1,0,3,2,5,4,7,6};   // SHUFFLE_MASK(1,1,1,1)
  const int P2[8] = {2,3,0,1,6,7,4,5};   // NETWORK_64BIT_3
  const int P3[8] = {3,2,1,0,7,6,5,4};   // NETWORK_64BIT_1
  const int P7[8] = {7,6,5,4,3,2,1,0};   // NETWORK_64BIT_2 (reverse)
  xss_stage(k, a, P1, 0xAA);
  xss_stage(k, a, P3, 0xCC);
  xss_stage(k, a, P1, 0xAA);
  xss_stage(k, a, P7, 0xF0);
  xss_stage(k, a, P2, 0xCC);
  xss_stage(k, a, P1, 0xAA);
}

__device__ __forceinline__ void xss_merge8(long long* k, int* a) {
  const int P1[8] = {1,0,3,2,5,4,7,6};
  const int P2[8] = {2,3,0,1,6,7,4,5};
  const int P4[8] = {4,5,6,7,0,1,2,3};   // NETWORK_64BIT_4
  xss_stage(k, a, P4, 0xF0);
  xss_stage(k, a, P2, 0xCC);
  xss_stage(k, a, P1, 0xAA);
}

// bitonic_merge_n_vec<2> (new xss): rev, COEX, rev BACK, then merge_zmm both
__device__ __forceinline__ void xss_merge_pair(long long* kA, int* aA,
                                               long long* kB, int* aB) {
  xss_rev(kB, aB);
  xss_coex(kA, aA, kB, aB);
  xss_rev(kB, aB);
  xss_merge8(kA, aA);
  xss_merge8(kB, aB);
}

// ---------------------------------------------------------------------------
// Kernel 1: per-box params + exact numpy(avx512 xss) argsort order
// ---------------------------------------------------------------------------
__global__ void prep_kernel(const int* __restrict__ boxes_raw,
                            int* __restrict__ wsi, float* __restrict__ th) {
  if (threadIdx.x != 0 || blockIdx.x != 0) return;

  // Detect raw-int64 upload: odd int32 slots all zero (y-coords are >=8,
  // so int32-converted data always has nonzero odd slots).
  bool i64mode = true;
  for (int i = 1; i < NBOX*4; i += 2) {
    if (boxes_raw[i] != 0) { i64mode = false; break; }
  }

  int widths[NBOX];
  double t00[NBOX], t02[NBOX], t11[NBOX], t12[NBOX];
  for (int n = 0; n < NBOX; ++n) {
    int x1, y1, x3, y3;
    if (i64mode) {
      x1 = boxes_raw[(n*4+0)*2]; y1 = boxes_raw[(n*4+1)*2];
      x3 = boxes_raw[(n*4+2)*2]; y3 = boxes_raw[(n*4+3)*2];
    } else {
      x1 = boxes_raw[n*4+0]; y1 = boxes_raw[n*4+1];
      x3 = boxes_raw[n*4+2]; y3 = boxes_raw[n*4+3];
    }
    int bw = x3 > x1 ? x3-x1 : x1-x3;
    int bh = y3 > y1 ? y3-y1 : y1-y3;
    int bmax = bw > bh ? bw : bh;
    int bmin = bw > bh ? bh : bw;
    if (bmin < 1) bmin = 1;                    // safety
    int wb = (CROPH*bmax + bmin - 1) / bmin;   // == ceil(28*box_w/box_h)
    if (wb > IMG) wb = IMG;
    widths[n] = wb;
    double a = (double)(x3-x1) / (double)wb;      // Ai[0,0]
    double e = (double)(y3-y1) / (double)CROPH;   // Ai[1,1]
    t00[n] = a;
    t02[n] = (double)x1 * (2.0/(double)IMG) + a - 1.0;
    t11[n] = e;
    t12[n] = (double)y1 * (2.0/(double)IMG) + e - 1.0;
  }

  // ---- new-xss argsort_n_vec<numVecs=4> emulation (N=32, full loads) ----
  long long K[4][8]; int A[4][8];
  for (int v = 0; v < 4; ++v)
    for (int j = 0; j < 8; ++j) {
      A[v][j] = 8*v + j;
      K[v][j] = (long long)widths[8*v + j];
    }
  // 1) sort each vector
  for (int v = 0; v < 4; ++v) xss_sort8(K[v], A[v]);
  // 2) fullmerge, numPer=2: pairs (0,1) and (2,3)
  xss_merge_pair(K[0], A[0], K[1], A[1]);
  xss_merge_pair(K[2], A[2], K[3], A[3]);
  // 3) fullmerge, numPer=4: bitonic_merge_n_vec<4>
  xss_rev(K[3], A[3]); xss_coex(K[0], A[0], K[3], A[3]); xss_rev(K[3], A[3]);
  xss_rev(K[2], A[2]); xss_coex(K[1], A[1], K[2], A[2]); xss_rev(K[2], A[2]);
  xss_coex(K[0], A[0], K[1], A[1]);     // clean: (0,1)
  xss_coex(K[2], A[2], K[3], A[3]);     // clean: (2,3)
  for (int v = 0; v < 4; ++v) xss_merge8(K[v], A[v]);

  int asc[NBOX];
  for (int v = 0; v < 4; ++v)
    for (int j = 0; j < 8; ++j) asc[8*v + j] = A[v][j];

  int maxw = 0;
  for (int i = 0; i < NBOX; ++i) if (widths[i] > maxw) maxw = widths[i];
  wsi[0] = maxw;
  for (int i = 0; i < NBOX; ++i) {              // order = argsort(asc)[::-1]
    int src = asc[NBOX-1-i];
    wsi[1+i]  = widths[src];
    th[i*4+0] = (float)t00[src];
    th[i*4+1] = (float)t02[src];
    th[i*4+2] = (float)t11[src];
    th[i*4+3] = (float)t12[src];
  }
}

// ---------------------------------------------------------------------------
__device__ __forceinline__ float sample_feat(const float* __restrict__ fc,
                                             float ix, float iy) {
  float xf = floorf(ix), yf = floorf(iy);
  int x0 = (int)xf, y0 = (int)yf;
  float wx = ix - xf, wy = iy - yf;
  x0 = min(max(x0, 0), IMG-2);     // coords provably interior for this input
  y0 = min(max(y0, 0), IMG-2);
  const float* r0 = fc + y0*IMG + x0;
  float v00 = r0[0], v10 = r0[1], v01 = r0[IMG], v11 = r0[IMG+1];
  return (1.f-wy)*((1.f-wx)*v00 + wx*v10) + wy*((1.f-wx)*v01 + wx*v11);
}

__device__ __forceinline__ float crop_val(const float* __restrict__ feat, int c,
                                          int width, float t00, float t02,
                                          float t11, float t12, int h, int w) {
  if (w >= width) return 0.f;
  float gx = -1.f + (2.f/255.f)*(float)w;
  float gy = -1.f + (2.f/255.f)*(float)h;
  float ix = (t00*gx + t02 + 1.f)*127.5f;
  float iy = (t11*gy + t12 + 1.f)*127.5f;
  return sample_feat(feat + c*IMG*IMG, ix, iy);
}

// ---------------------------------------------------------------------------
// Kernel 2: sorted+masked cropped tensor [NBOX][NCH][28][256] into ws
// ---------------------------------------------------------------------------
__global__ void warp_kernel(const float* __restrict__ feat,
                            const int* __restrict__ wsi,
                            const float* __restrict__ th,
                            float* __restrict__ crop) {
  int w = threadIdx.x;    // 0..255
  int h = blockIdx.x;     // 0..27
  int c = blockIdx.y;     // 0..31
  int n = blockIdx.z;     // 0..31  (already sorted order)
  int width = wsi[1+n];
  float val = crop_val(feat, c, width,
                       th[n*4+0], th[n*4+1], th[n*4+2], th[n*4+3], h, w);
  crop[(((n*NCH)+c)*CROPH + h)*MAXCAP + w] = val;
}

// ---------------------------------------------------------------------------
// Kernel 3: bilinear resize (align_corners=True) to 224x224
// ---------------------------------------------------------------------------
__global__ void resize_kernel(const float* __restrict__ crop,
                              const int* __restrict__ wsi,
                              float* __restrict__ out) {
  int t = blockIdx.x*blockDim.x + threadIdx.x;   // 0..50175
  int p = t / OUTHW, q = t - p*OUTHW;
  int c = blockIdx.y, n = blockIdx.z;
  int maxw = wsi[0];
  float py = (float)p * ((float)(CROPH-1)/(float)(OUTHW-1));
  float qx = (float)q * ((float)(maxw-1)/(float)(OUTHW-1));
  float hf = floorf(py); int h0 = (int)hf; if (h0 > CROPH-2) h0 = CROPH-2;
  float ty = py - (float)h0;
  float xf = floorf(qx); int x0 = (int)xf; if (x0 > maxw-2) x0 = maxw-2;
  float tx = qx - (float)x0;
  const float* b = crop + ((n*NCH + c)*CROPH + h0)*MAXCAP + x0;
  float v00 = b[0], v10 = b[1], v01 = b[MAXCAP], v11 = b[MAXCAP+1];
  out[((n*NCH + c)*OUTHW + p)*OUTHW + q] =
      (1.f-ty)*((1.f-tx)*v00 + tx*v10) + ty*((1.f-tx)*v01 + tx*v11);
}

// Fallback if ws can't hold the crop buffer: compute crop values on the fly.
__global__ void fused_kernel(const float* __restrict__ feat,
                             const int* __restrict__ wsi,
                             const float* __restrict__ th,
                             float* __restrict__ out) {
  int t = blockIdx.x*blockDim.x + threadIdx.x;
  int p = t / OUTHW, q = t - p*OUTHW;
  int c = blockIdx.y, n = blockIdx.z;
  int maxw = wsi[0];
  int width = wsi[1+n];
  float t00 = th[n*4+0], t02 = th[n*4+1], t11 = th[n*4+2], t12 = th[n*4+3];
  float py = (float)p * ((float)(CROPH-1)/(float)(OUTHW-1));
  float qx = (float)q * ((float)(maxw-1)/(float)(OUTHW-1));
  float hf = floorf(py); int h0 = (int)hf; if (h0 > CROPH-2) h0 = CROPH-2;
  float ty = py - (float)h0;
  float xf = floorf(qx); int x0 = (int)xf; if (x0 > maxw-2) x0 = maxw-2;
  float tx = qx - (float)x0;
  float v00 = crop_val(feat, c, width, t00, t02, t11, t12, h0,   x0);
  float v10 = crop_val(feat, c, width, t00, t02, t11, t12, h0,   x0+1);
  float v01 = crop_val(feat, c, width, t00, t02, t11, t12, h0+1, x0);
  float v11 = crop_val(feat, c, width, t00, t02, t11, t12, h0+1, x0+1);
  out[((n*NCH + c)*OUTHW + p)*OUTHW + q] =
      (1.f-ty)*((1.f-tx)*v00 + tx*v10) + ty*((1.f-tx)*v01 + tx*v11);
}

// ---------------------------------------------------------------------------
extern "C" void kernel_launch(void* const* d_in, const int* in_sizes, int n_in,
                              void* d_out, int out_size, void* d_ws, size_t ws_size,
                              hipStream_t stream) {
  const float* feat  = (const float*)d_in[0];
  const int*   boxes = (const int*)d_in[1];
  float* out = (float*)d_out;

  int*   wsi  = (int*)d_ws;                       // [0]=maxw, [1..32]=sorted widths
  float* th   = (float*)((char*)d_ws + 512);      // [32][4] sorted thetas
  float* crop = (float*)((char*)d_ws + 4096);     // [32][32][28][256] f32

  size_t need = 4096 + (size_t)NBOX*NCH*CROPH*MAXCAP*sizeof(float);

  prep_kernel<<<1, 64, 0, stream>>>(boxes, wsi, th);
  if (ws_size >= need) {
    warp_kernel<<<dim3(CROPH, NCH, NBOX), MAXCAP, 0, stream>>>(feat, wsi, th, crop);
    resize_kernel<<<dim3((OUTHW*OUTHW)/256, NCH, NBOX), 256, 0, stream>>>(crop, wsi, out);
  } else {
    fused_kernel<<<dim3((OUTHW*OUTHW)/256, NCH, NBOX), 256, 0, stream>>>(feat, wsi, th, out);
  }
}

// Round 5
// 224.854 us; speedup vs baseline: 1.3556x; 1.3556x over previous
//
#include <hip/hip_runtime.h>

#define NBOX   32
#define NCH    32
#define IMG    256
#define CROPH  28
#define OUTHW  224
#define TSTR   257   // LDS tile row stride (28x257 floats = 28.8 KB)

// ===========================================================================
// Lane-exact scalar emulation of x86-simd-sort (numpy >=2.x vendored,
// xss_network_keyvaluesort.hpp) avx512 argsort for N=32 int64 keys.
// PROVEN in R4 — do not touch. Tie rules: cmp_merge keeps own index on
// equality; COEX min<-first operand's index, max<-second's.
// ===========================================================================
__device__ __forceinline__ void xss_stage(long long* k, int* a,
                                          const int* p, int mask) {
  long long nk[8]; int na[8];
  for (int j = 0; j < 8; ++j) {
    long long kb = k[p[j]]; int ab = a[p[j]];
    long long mn = (kb < k[j]) ? kb : k[j];
    long long mx = (kb < k[j]) ? k[j] : kb;
    long long sel = ((mask >> j) & 1) ? mx : mn;
    na[j] = (sel == k[j]) ? a[j] : ab;
    nk[j] = sel;
  }
  for (int j = 0; j < 8; ++j) { k[j] = nk[j]; a[j] = na[j]; }
}
__device__ __forceinline__ void xss_rev(long long* k, int* a) {
  for (int j = 0; j < 4; ++j) {
    long long tk = k[j]; k[j] = k[7-j]; k[7-j] = tk;
    int ta = a[j]; a[j] = a[7-j]; a[7-j] = ta;
  }
}
__device__ __forceinline__ void xss_coex(long long* k1, int* a1,
                                         long long* k2, int* a2) {
  for (int j = 0; j < 8; ++j) {
    long long ka = k1[j], kb = k2[j];
    int aa = a1[j], ab = a2[j];
    bool alem = (ka <= kb);
    k1[j] = alem ? ka : kb;  a1[j] = alem ? aa : ab;
    k2[j] = alem ? kb : ka;  a2[j] = alem ? ab : aa;
  }
}
__device__ __forceinline__ void xss_sort8(long long* k, int* a) {
  const int P1[8] = {1,0,3,2,5,4,7,6};
  const int P2[8] = {2,3,0,1,6,7,4,5};
  const int P3[8] = {3,2,1,0,7,6,5,4};
  const int P7[8] = {7,6,5,4,3,2,1,0};
  xss_stage(k, a, P1, 0xAA);
  xss_stage(k, a, P3, 0xCC);
  xss_stage(k, a, P1, 0xAA);
  xss_stage(k, a, P7, 0xF0);
  xss_stage(k, a, P2, 0xCC);
  xss_stage(k, a, P1, 0xAA);
}
__device__ __forceinline__ void xss_merge8(long long* k, int* a) {
  const int P1[8] = {1,0,3,2,5,4,7,6};
  const int P2[8] = {2,3,0,1,6,7,4,5};
  const int P4[8] = {4,5,6,7,0,1,2,3};
  xss_stage(k, a, P4, 0xF0);
  xss_stage(k, a, P2, 0xCC);
  xss_stage(k, a, P1, 0xAA);
}
__device__ __forceinline__ void xss_merge_pair(long long* kA, int* aA,
                                               long long* kB, int* aB) {
  xss_rev(kB, aB);
  xss_coex(kA, aA, kB, aB);
  xss_rev(kB, aB);
  xss_merge8(kA, aA);
  xss_merge8(kB, aB);
}

// ---------------------------------------------------------------------------
// Kernel 1: per-box params (32 lanes parallel) + lane-0 exact xss argsort
// ---------------------------------------------------------------------------
__global__ void prep_kernel(const int* __restrict__ boxes_raw,
                            int* __restrict__ wsi, float* __restrict__ th) {
  __shared__ int    s_w[NBOX];
  __shared__ double s_t[NBOX][4];
  __shared__ int    s_asc[NBOX];
  __shared__ int    s_i64;
  int lane = threadIdx.x;

  if (lane == 0) {
    int i64 = 1;
    for (int i = 1; i < NBOX*4; i += 2)
      if (boxes_raw[i] != 0) { i64 = 0; break; }
    s_i64 = i64;
  }
  __syncthreads();
  bool i64mode = (s_i64 != 0);

  if (lane < NBOX) {
    int x1, y1, x3, y3;
    if (i64mode) {
      x1 = boxes_raw[(lane*4+0)*2]; y1 = boxes_raw[(lane*4+1)*2];
      x3 = boxes_raw[(lane*4+2)*2]; y3 = boxes_raw[(lane*4+3)*2];
    } else {
      x1 = boxes_raw[lane*4+0]; y1 = boxes_raw[lane*4+1];
      x3 = boxes_raw[lane*4+2]; y3 = boxes_raw[lane*4+3];
    }
    int bw = x3 > x1 ? x3-x1 : x1-x3;
    int bh = y3 > y1 ? y3-y1 : y1-y3;
    int bmax = bw > bh ? bw : bh;
    int bmin = bw > bh ? bh : bw;
    if (bmin < 1) bmin = 1;
    int wb = (CROPH*bmax + bmin - 1) / bmin;   // ceil(28*box_w/box_h)
    if (wb > IMG) wb = IMG;
    s_w[lane] = wb;
    double a = (double)(x3-x1) / (double)wb;
    double e = (double)(y3-y1) / (double)CROPH;
    s_t[lane][0] = a;
    s_t[lane][1] = (double)x1 * (2.0/(double)IMG) + a - 1.0;
    s_t[lane][2] = e;
    s_t[lane][3] = (double)y1 * (2.0/(double)IMG) + e - 1.0;
  }
  __syncthreads();

  if (lane == 0) {
    long long K[4][8]; int A[4][8];
    for (int v = 0; v < 4; ++v)
      for (int j = 0; j < 8; ++j) {
        A[v][j] = 8*v + j;
        K[v][j] = (long long)s_w[8*v + j];
      }
    for (int v = 0; v < 4; ++v) xss_sort8(K[v], A[v]);
    xss_merge_pair(K[0], A[0], K[1], A[1]);
    xss_merge_pair(K[2], A[2], K[3], A[3]);
    xss_rev(K[3], A[3]); xss_coex(K[0], A[0], K[3], A[3]); xss_rev(K[3], A[3]);
    xss_rev(K[2], A[2]); xss_coex(K[1], A[1], K[2], A[2]); xss_rev(K[2], A[2]);
    xss_coex(K[0], A[0], K[1], A[1]);
    xss_coex(K[2], A[2], K[3], A[3]);
    for (int v = 0; v < 4; ++v) xss_merge8(K[v], A[v]);
    for (int v = 0; v < 4; ++v)
      for (int j = 0; j < 8; ++j) s_asc[8*v + j] = A[v][j];
    int maxw = 0;
    for (int i = 0; i < NBOX; ++i) if (s_w[i] > maxw) maxw = s_w[i];
    wsi[0] = maxw;
  }
  __syncthreads();

  if (lane < NBOX) {                    // order = argsort(asc)[::-1]
    int src = s_asc[NBOX-1-lane];
    wsi[1+lane]   = s_w[src];
    th[lane*4+0]  = (float)s_t[src][0];
    th[lane*4+1]  = (float)s_t[src][1];
    th[lane*4+2]  = (float)s_t[src][2];
    th[lane*4+3]  = (float)s_t[src][3];
  }
}

// ---------------------------------------------------------------------------
// Kernel 2: fused warp + resize. One block per (n,c); 28x256 crop tile lives
// in LDS (28.8 KB -> 4 blocks/CU), never touches HBM.
//   Stage:  thread w computes crop[h][w] for h=0..27 (4-tap bilinear; coords
//           are separable and provably interior -> clamps never bind).
//   Resize: thread q marches down its output column; x-lerp weights fixed,
//           vtop/vbot re-loaded only when h0 increments (2 LDS reads/row).
// ---------------------------------------------------------------------------
__global__ __launch_bounds__(256)
void fused_kernel(const float* __restrict__ feat,
                  const int* __restrict__ wsi,
                  const float* __restrict__ th,
                  float* __restrict__ out) {
  __shared__ float tile[CROPH][TSTR];
  int c = blockIdx.x, n = blockIdx.y;
  int tid = threadIdx.x;

  int maxw  = wsi[0];
  int width = wsi[1+n];
  float t00 = th[n*4+0], t02 = th[n*4+1], t11 = th[n*4+2], t12 = th[n*4+3];

  // ---- stage crop tile ----
  const float* fc = feat + c*IMG*IMG;
  int w = tid;                          // 0..255
  if (w < width) {
    float gx = -1.f + (2.f/255.f)*(float)w;
    float ix = (t00*gx + t02 + 1.f)*127.5f;
    float xf = floorf(ix);
    int   x0 = (int)xf;
    x0 = min(max(x0, 0), IMG-2);        // never binds (ix in [0, 255-t00])
    float wx = ix - xf;
    const float* col = fc + x0;
    for (int h = 0; h < CROPH; ++h) {
      float gy = -1.f + (2.f/255.f)*(float)h;
      float iy = (t11*gy + t12 + 1.f)*127.5f;
      float yf = floorf(iy);
      int   y0 = (int)yf;
      y0 = min(max(y0, 0), IMG-2);
      float wy = iy - yf;
      const float* r0 = col + y0*IMG;
      float a0 = r0[0],   a1 = r0[1];
      float b0 = r0[IMG], b1 = r0[IMG+1];
      float ta = a0 + wx*(a1-a0);
      float tb = b0 + wx*(b1-b0);
      tile[h][w] = ta + wy*(tb-ta);
    }
  } else {
    for (int h = 0; h < CROPH; ++h) tile[h][w] = 0.f;
  }
  __syncthreads();

  // ---- resize 28 x maxw -> 224 x 224, bilinear align_corners=True ----
  int q = tid;
  if (q < OUTHW) {
    float qx = (float)q * ((float)(maxw-1)/(float)(OUTHW-1));
    float xf = floorf(qx);
    int   xi = (int)xf; if (xi > maxw-2) xi = maxw-2;
    float tx = qx - (float)xi;

    const float pys = (float)(CROPH-1)/(float)(OUTHW-1);
    float* op = out + ((size_t)(n*NCH + c)*OUTHW)*OUTHW + q;

    int cur = -2;
    float vtop = 0.f, vbot = 0.f;
    for (int p = 0; p < OUTHW; ++p) {
      float py = (float)p * pys;
      int h0 = (int)py; if (h0 > CROPH-2) h0 = CROPH-2;
      float ty = py - (float)h0;
      if (h0 != cur) {
        if (h0 == cur+1) {
          vtop = vbot;
        } else {
          float a0 = tile[h0][xi], a1 = tile[h0][xi+1];
          vtop = a0 + tx*(a1-a0);
        }
        float b0 = tile[h0+1][xi], b1 = tile[h0+1][xi+1];
        vbot = b0 + tx*(b1-b0);
        cur = h0;
      }
      *op = vtop + ty*(vbot - vtop);
      op += OUTHW;
    }
  }
}

// ---------------------------------------------------------------------------
extern "C" void kernel_launch(void* const* d_in, const int* in_sizes, int n_in,
                              void* d_out, int out_size, void* d_ws, size_t ws_size,
                              hipStream_t stream) {
  const float* feat  = (const float*)d_in[0];
  const int*   boxes = (const int*)d_in[1];
  float* out = (float*)d_out;

  int*   wsi = (int*)d_ws;                    // [0]=maxw, [1..32]=sorted widths
  float* th  = (float*)((char*)d_ws + 512);   // [32][4] sorted thetas

  prep_kernel<<<1, 64, 0, stream>>>(boxes, wsi, th);
  fused_kernel<<<dim3(NCH, NBOX), 256, 0, stream>>>(feat, wsi, th, out);
}

// Round 6
// 220.826 us; speedup vs baseline: 1.3803x; 1.0182x over previous
//
#include <hip/hip_runtime.h>

#define NBOX   32
#define NCH    32
#define IMG    256
#define CROPH  28
#define OUTHW  224
#define TSTR   257   // LDS tile row stride (28x257 floats = 28.8 KB)

// ===========================================================================
// Lane-exact scalar emulation of x86-simd-sort (numpy >=2.x vendored,
// xss_network_keyvaluesort.hpp) avx512 argsort for N=32 int64 keys.
// PROVEN in R4 — do not touch. Tie rules: cmp_merge keeps own index on
// equality; COEX min<-first operand's index, max<-second's.
// ===========================================================================
__device__ __forceinline__ void xss_stage(long long* k, int* a,
                                          const int* p, int mask) {
  long long nk[8]; int na[8];
  for (int j = 0; j < 8; ++j) {
    long long kb = k[p[j]]; int ab = a[p[j]];
    long long mn = (kb < k[j]) ? kb : k[j];
    long long mx = (kb < k[j]) ? k[j] : kb;
    long long sel = ((mask >> j) & 1) ? mx : mn;
    na[j] = (sel == k[j]) ? a[j] : ab;
    nk[j] = sel;
  }
  for (int j = 0; j < 8; ++j) { k[j] = nk[j]; a[j] = na[j]; }
}
__device__ __forceinline__ void xss_rev(long long* k, int* a) {
  for (int j = 0; j < 4; ++j) {
    long long tk = k[j]; k[j] = k[7-j]; k[7-j] = tk;
    int ta = a[j]; a[j] = a[7-j]; a[7-j] = ta;
  }
}
__device__ __forceinline__ void xss_coex(long long* k1, int* a1,
                                         long long* k2, int* a2) {
  for (int j = 0; j < 8; ++j) {
    long long ka = k1[j], kb = k2[j];
    int aa = a1[j], ab = a2[j];
    bool alem = (ka <= kb);
    k1[j] = alem ? ka : kb;  a1[j] = alem ? aa : ab;
    k2[j] = alem ? kb : ka;  a2[j] = alem ? ab : aa;
  }
}
__device__ __forceinline__ void xss_sort8(long long* k, int* a) {
  const int P1[8] = {1,0,3,2,5,4,7,6};
  const int P2[8] = {2,3,0,1,6,7,4,5};
  const int P3[8] = {3,2,1,0,7,6,5,4};
  const int P7[8] = {7,6,5,4,3,2,1,0};
  xss_stage(k, a, P1, 0xAA);
  xss_stage(k, a, P3, 0xCC);
  xss_stage(k, a, P1, 0xAA);
  xss_stage(k, a, P7, 0xF0);
  xss_stage(k, a, P2, 0xCC);
  xss_stage(k, a, P1, 0xAA);
}
__device__ __forceinline__ void xss_merge8(long long* k, int* a) {
  const int P1[8] = {1,0,3,2,5,4,7,6};
  const int P2[8] = {2,3,0,1,6,7,4,5};
  const int P4[8] = {4,5,6,7,0,1,2,3};
  xss_stage(k, a, P4, 0xF0);
  xss_stage(k, a, P2, 0xCC);
  xss_stage(k, a, P1, 0xAA);
}
__device__ __forceinline__ void xss_merge_pair(long long* kA, int* aA,
                                               long long* kB, int* aB) {
  xss_rev(kB, aB);
  xss_coex(kA, aA, kB, aB);
  xss_rev(kB, aB);
  xss_merge8(kA, aA);
  xss_merge8(kB, aB);
}

// ---------------------------------------------------------------------------
// Kernel 1: per-box params (32 lanes parallel) + lane-0 exact xss argsort
// ---------------------------------------------------------------------------
__global__ void prep_kernel(const int* __restrict__ boxes_raw,
                            int* __restrict__ wsi, float* __restrict__ th) {
  __shared__ int    s_w[NBOX];
  __shared__ double s_t[NBOX][4];
  __shared__ int    s_asc[NBOX];
  __shared__ int    s_i64;
  int lane = threadIdx.x;

  if (lane == 0) {
    int i64 = 1;
    for (int i = 1; i < NBOX*4; i += 2)
      if (boxes_raw[i] != 0) { i64 = 0; break; }
    s_i64 = i64;
  }
  __syncthreads();
  bool i64mode = (s_i64 != 0);

  if (lane < NBOX) {
    int x1, y1, x3, y3;
    if (i64mode) {
      x1 = boxes_raw[(lane*4+0)*2]; y1 = boxes_raw[(lane*4+1)*2];
      x3 = boxes_raw[(lane*4+2)*2]; y3 = boxes_raw[(lane*4+3)*2];
    } else {
      x1 = boxes_raw[lane*4+0]; y1 = boxes_raw[lane*4+1];
      x3 = boxes_raw[lane*4+2]; y3 = boxes_raw[lane*4+3];
    }
    int bw = x3 > x1 ? x3-x1 : x1-x3;
    int bh = y3 > y1 ? y3-y1 : y1-y3;
    int bmax = bw > bh ? bw : bh;
    int bmin = bw > bh ? bh : bw;
    if (bmin < 1) bmin = 1;
    int wb = (CROPH*bmax + bmin - 1) / bmin;   // ceil(28*box_w/box_h)
    if (wb > IMG) wb = IMG;
    s_w[lane] = wb;
    double a = (double)(x3-x1) / (double)wb;
    double e = (double)(y3-y1) / (double)CROPH;
    s_t[lane][0] = a;
    s_t[lane][1] = (double)x1 * (2.0/(double)IMG) + a - 1.0;
    s_t[lane][2] = e;
    s_t[lane][3] = (double)y1 * (2.0/(double)IMG) + e - 1.0;
  }
  __syncthreads();

  if (lane == 0) {
    long long K[4][8]; int A[4][8];
    for (int v = 0; v < 4; ++v)
      for (int j = 0; j < 8; ++j) {
        A[v][j] = 8*v + j;
        K[v][j] = (long long)s_w[8*v + j];
      }
    for (int v = 0; v < 4; ++v) xss_sort8(K[v], A[v]);
    xss_merge_pair(K[0], A[0], K[1], A[1]);
    xss_merge_pair(K[2], A[2], K[3], A[3]);
    xss_rev(K[3], A[3]); xss_coex(K[0], A[0], K[3], A[3]); xss_rev(K[3], A[3]);
    xss_rev(K[2], A[2]); xss_coex(K[1], A[1], K[2], A[2]); xss_rev(K[2], A[2]);
    xss_coex(K[0], A[0], K[1], A[1]);
    xss_coex(K[2], A[2], K[3], A[3]);
    for (int v = 0; v < 4; ++v) xss_merge8(K[v], A[v]);
    for (int v = 0; v < 4; ++v)
      for (int j = 0; j < 8; ++j) s_asc[8*v + j] = A[v][j];
    int maxw = 0;
    for (int i = 0; i < NBOX; ++i) if (s_w[i] > maxw) maxw = s_w[i];
    wsi[0] = maxw;
  }
  __syncthreads();

  if (lane < NBOX) {                    // order = argsort(asc)[::-1]
    int src = s_asc[NBOX-1-lane];
    wsi[1+lane]   = s_w[src];
    th[lane*4+0]  = (float)s_t[src][0];
    th[lane*4+1]  = (float)s_t[src][1];
    th[lane*4+2]  = (float)s_t[src][2];
    th[lane*4+3]  = (float)s_t[src][3];
  }
}

// ---------------------------------------------------------------------------
// Kernel 2: fused warp + resize. One block per (n,c); 28x256 crop tile in LDS.
//   Stage:  thread w computes crop[h][w] for h=0..27.
//   Resize: wave-per-row mapping — wave v handles rows p = v,v+4,...; lane l
//           (l<56) owns columns 4l..4l+3 and stores one float4 per row
//           (896 B contiguous per wave-store vs 256 B in R5's column map).
//           h0/ty are wave-uniform; x-lerp weights computed once per lane;
//           vtop/vbot re-lerped only when h0 increments (h0 step is 0 or 1
//           since 4 rows advance py by 4*27/223 = 0.484).
// ---------------------------------------------------------------------------
__global__ __launch_bounds__(256)
void fused_kernel(const float* __restrict__ feat,
                  const int* __restrict__ wsi,
                  const float* __restrict__ th,
                  float* __restrict__ out) {
  __shared__ float tile[CROPH][TSTR];
  int c = blockIdx.x, n = blockIdx.y;
  int tid = threadIdx.x;

  int maxw  = wsi[0];
  int width = wsi[1+n];
  float t00 = th[n*4+0], t02 = th[n*4+1], t11 = th[n*4+2], t12 = th[n*4+3];

  // ---- stage crop tile ----
  const float* fc = feat + c*IMG*IMG;
  int w = tid;                          // 0..255
  if (w < width) {
    float gx = -1.f + (2.f/255.f)*(float)w;
    float ix = (t00*gx + t02 + 1.f)*127.5f;
    float xf = floorf(ix);
    int   x0 = (int)xf;
    x0 = min(max(x0, 0), IMG-2);        // never binds (coords interior)
    float wx = ix - xf;
    const float* col = fc + x0;
    for (int h = 0; h < CROPH; ++h) {
      float gy = -1.f + (2.f/255.f)*(float)h;
      float iy = (t11*gy + t12 + 1.f)*127.5f;
      float yf = floorf(iy);
      int   y0 = (int)yf;
      y0 = min(max(y0, 0), IMG-2);
      float wy = iy - yf;
      const float* r0 = col + y0*IMG;
      float a0 = r0[0],   a1 = r0[1];
      float b0 = r0[IMG], b1 = r0[IMG+1];
      float ta = a0 + wx*(a1-a0);
      float tb = b0 + wx*(b1-b0);
      tile[h][w] = ta + wy*(tb-ta);
    }
  } else {
    for (int h = 0; h < CROPH; ++h) tile[h][w] = 0.f;
  }
  __syncthreads();

  // ---- resize 28 x maxw -> 224 x 224, bilinear align_corners=True ----
  int wave = tid >> 6;                  // 0..3
  int lane = tid & 63;                  // 0..63
  if (lane < OUTHW/4) {                 // 56 active lanes
    int qb = lane * 4;
    const float xs = (float)(maxw-1)/(float)(OUTHW-1);
    float tx[4]; int xi[4];
#pragma unroll
    for (int j = 0; j < 4; ++j) {
      float qx = (float)(qb+j) * xs;
      float xf = floorf(qx);
      int x = (int)xf; if (x > maxw-2) x = maxw-2;
      xi[j] = x; tx[j] = qx - (float)x;
    }
    const float pys = (float)(CROPH-1)/(float)(OUTHW-1);
    float* op = out + ((size_t)(n*NCH + c))*OUTHW*OUTHW + qb;

    int cur = -2;
    float vtop[4], vbot[4];
    for (int p = wave; p < OUTHW; p += 4) {
      float py = (float)p * pys;
      int h0 = (int)py; if (h0 > CROPH-2) h0 = CROPH-2;
      float ty = py - (float)h0;
      if (h0 != cur) {
        if (h0 == cur+1) {
#pragma unroll
          for (int j = 0; j < 4; ++j) vtop[j] = vbot[j];
        } else {
#pragma unroll
          for (int j = 0; j < 4; ++j) {
            float a0 = tile[h0][xi[j]], a1 = tile[h0][xi[j]+1];
            vtop[j] = a0 + tx[j]*(a1-a0);
          }
        }
#pragma unroll
        for (int j = 0; j < 4; ++j) {
          float b0 = tile[h0+1][xi[j]], b1 = tile[h0+1][xi[j]+1];
          vbot[j] = b0 + tx[j]*(b1-b0);
        }
        cur = h0;
      }
      float4 o;
      o.x = vtop[0] + ty*(vbot[0]-vtop[0]);
      o.y = vtop[1] + ty*(vbot[1]-vtop[1]);
      o.z = vtop[2] + ty*(vbot[2]-vtop[2]);
      o.w = vtop[3] + ty*(vbot[3]-vtop[3]);
      *(float4*)(op + (size_t)p*OUTHW) = o;
    }
  }
}

// ---------------------------------------------------------------------------
extern "C" void kernel_launch(void* const* d_in, const int* in_sizes, int n_in,
                              void* d_out, int out_size, void* d_ws, size_t ws_size,
                              hipStream_t stream) {
  const float* feat  = (const float*)d_in[0];
  const int*   boxes = (const int*)d_in[1];
  float* out = (float*)d_out;

  int*   wsi = (int*)d_ws;                    // [0]=maxw, [1..32]=sorted widths
  float* th  = (float*)((char*)d_ws + 512);   // [32][4] sorted thetas

  prep_kernel<<<1, 64, 0, stream>>>(boxes, wsi, th);
  fused_kernel<<<dim3(NCH, NBOX), 256, 0, stream>>>(feat, wsi, th, out);
}